// Round 7
// baseline (1384.539 us; speedup 1.0000x reference)
//
#include <hip/hip_runtime.h>
#include <hip/hip_bf16.h>
#include <math.h>

// Problem constants (fixed by the reference)
#define TT   799
#define BB   8
#define DD   512
#define HH   8
#define HDD  64
#define MMEM 6
#define RRCB 24
#define KLL  798
#define TQ   798            // query rows actually needed (row 798 unused)
#define NROWS (TQ * BB)     // 6384
#define NHEADS 64           // B*H
#define NEG_INF (-INFINITY)

#define TB   16             // t-rows per attention block
#define CH   64             // keys per MFMA chunk
#define NCH  13             // 13*64 = 832 >= 798

static_assert(NROWS == 6384, "");

typedef __attribute__((ext_vector_type(8))) short short8;
typedef __attribute__((ext_vector_type(4))) float f32x4;

__device__ __forceinline__ unsigned short f2bf(float x) {
    union { float f; unsigned u; } c; c.f = x;
    unsigned r = c.u + 0x7FFFu + ((c.u >> 16) & 1u);   // RNE
    return (unsigned short)(r >> 16);
}
__device__ __forceinline__ float bf2f(unsigned short b) {
    union { unsigned u; float f; } c; c.u = ((unsigned)b) << 16; return c.f;
}

// Classify attention_mask storage from byte patterns (sampled prefix).
// mode 0 = int32 (0/1), mode 1 = float32 (0.0/1.0), mode 2 = uint8 bool.
__global__ void detect_mask_kernel(const unsigned int* __restrict__ a,
                                   int* __restrict__ mode)
{
    __shared__ int c0s, cHs;
    if (threadIdx.x == 0) { c0s = 0; cHs = 0; }
    __syncthreads();
    int c0 = 0, cH = 0;
    const int ND = 4096;
    for (int i = threadIdx.x; i < ND; i += blockDim.x) {
        unsigned int w = a[i];
        if (w & 0x000000FFu) c0++;
        if (w & 0xFFFFFF00u) cH++;
    }
    atomicAdd(&c0s, c0); atomicAdd(&cHs, cH);
    __syncthreads();
    if (threadIdx.x == 0)
        *mode = (cHs == 0) ? 0 : ((c0s == 0) ? 1 : 2);
}

// MODE 0: q = x @ wq^T + bq  (scaled by 0.125, stored f32 (BH,798,64))
// MODE 1: kv = mem_rc @ wkv^T + bkv; k stored as bf16 hi/lo, v stored f32
template<int MODE>
__global__ __launch_bounds__(256)
void proj_kernel(const float* __restrict__ x,
                 const float* __restrict__ mems,
                 const float* __restrict__ w,
                 const float* __restrict__ bias,
                 float* __restrict__ q_s,
                 unsigned short* __restrict__ k_hi,
                 unsigned short* __restrict__ k_lo,
                 float* __restrict__ v_s)
{
    __shared__ float As[16][65];
    __shared__ float Ws[16][65];
    const int tid = threadIdx.x;
    const int m0 = blockIdx.x * 64;
    const int n0 = blockIdx.y * 64;
    const int tx = tid & 15;
    const int ty = tid >> 4;
    float acc[4][4] = {};

    for (int k0 = 0; k0 < DD; k0 += 16) {
        #pragma unroll
        for (int i = 0; i < 4; ++i) {
            int idx = tid + i * 256;
            int kk = idx & 15;
            int mm = idx >> 4;
            int m = m0 + mm;
            float va = 0.f;
            if (m < NROWS) {
                int row = m >> 3, b = m & 7;
                const float* src;
                if (MODE == 0) src = x + ((size_t)row * BB + b) * DD;
                else src = (row < MMEM) ? (mems + ((size_t)row * BB + b) * DD)
                                        : (x + ((size_t)(row - MMEM) * BB + b) * DD);
                va = src[k0 + kk];
            }
            As[kk][mm] = va;
            int n = n0 + mm;
            Ws[kk][mm] = w[(size_t)n * DD + k0 + kk];
        }
        __syncthreads();
        #pragma unroll
        for (int kk = 0; kk < 16; ++kk) {
            float a[4], wv[4];
            #pragma unroll
            for (int i = 0; i < 4; ++i) a[i] = As[kk][ty * 4 + i];
            #pragma unroll
            for (int j = 0; j < 4; ++j) wv[j] = Ws[kk][tx * 4 + j];
            #pragma unroll
            for (int i = 0; i < 4; ++i)
                #pragma unroll
                for (int j = 0; j < 4; ++j)
                    acc[i][j] = fmaf(a[i], wv[j], acc[i][j]);
        }
        __syncthreads();
    }

    #pragma unroll
    for (int i = 0; i < 4; ++i) {
        int m = m0 + ty * 4 + i;
        if (m >= NROWS) continue;
        int row = m >> 3, b = m & 7;
        #pragma unroll
        for (int j = 0; j < 4; ++j) {
            int n = n0 + tx * 4 + j;
            float v = acc[i][j] + bias[n];
            if (MODE == 0) {
                int h = n >> 6, hd = n & 63;
                q_s[((size_t)(b * HH + h) * TQ + row) * HDD + hd] = v * 0.125f;
            } else {
                if (n < DD) {
                    int h = n >> 6, hd = n & 63;
                    size_t o = ((size_t)(b * HH + h) * KLL + row) * HDD + hd;
                    unsigned short hi = f2bf(v);
                    k_hi[o] = hi;
                    k_lo[o] = f2bf(v - bf2f(hi));
                } else {
                    int n2 = n - DD;
                    int h = n2 >> 6, hd = n2 & 63;
                    v_s[((size_t)(b * HH + h) * KLL + row) * HDD + hd] = v;
                }
            }
        }
    }
}

// Attention v4: MFMA QK^T (bf16 hi/lo split, 6 MFMA per 16x16 tile),
// pass A = online stats, pass B = recompute + suppression-folded PV (VALU).
__global__ __launch_bounds__(256)
void attn_kernel(const float* __restrict__ q_s,
                 const unsigned short* __restrict__ kh_g,
                 const unsigned short* __restrict__ kl_g,
                 const float* __restrict__ v_s,
                 const int* __restrict__ lengths,
                 const void* __restrict__ amask,
                 const int* __restrict__ mask_mode,
                 const int* __restrict__ rpe,
                 const float* __restrict__ rpe_k,
                 const float* __restrict__ rpe_v,
                 float* __restrict__ attn_buf)
{
    const int t0 = blockIdx.x * TB;
    const int rows = min(TB, TQ - t0);
    const int n = blockIdx.y;
    const int b = n >> 3;
    const int h = n & 7;
    const int tid = threadIdx.x;
    const int wv = tid >> 6;            // wave 0..3 -> key tile
    const int quad = (tid >> 4) & 3;    // MFMA quad
    const int colk = tid & 15;          // key col within tile / A row
    const int r16 = tid >> 4;           // PV/qrk row 0..15
    const int g = tid & 15;             // hd quad

    __shared__ unsigned short kh_l[CH][72];
    __shared__ unsigned short kl_l[CH][72];
    __shared__ __align__(16) float v_l[32][68];
    __shared__ unsigned short qh_l[TB][72];
    __shared__ unsigned short ql_l[TB][72];
    __shared__ float qrk_l[TB][129];
    __shared__ float pr_l[TB][129];
    __shared__ __align__(16) float p_ch[TB][68];
    __shared__ float4 stats_l[4][TB];

    const int klen = lengths[b] + MMEM + RRCB;
    const int mode = *mask_mode;
    const int* am_i = (const int*)amask;
    const float* am_f = (const float*)amask;
    const unsigned char* am_b = (const unsigned char*)amask;

    // phase 0: q -> p_ch (f32 copy) + qh/ql (bf16 hi/lo); zero pr
    for (int i = tid; i < TB * 16; i += 256) {
        int rr = i >> 4, j4 = i & 15;
        float4 v = {0.f, 0.f, 0.f, 0.f};
        if (rr < rows) v = *(const float4*)(q_s + ((size_t)n * TQ + t0 + rr) * HDD + j4 * 4);
        *(float4*)&p_ch[rr][j4 * 4] = v;
        unsigned short h0 = f2bf(v.x), h1 = f2bf(v.y), h2 = f2bf(v.z), h3 = f2bf(v.w);
        qh_l[rr][j4 * 4 + 0] = h0; qh_l[rr][j4 * 4 + 1] = h1;
        qh_l[rr][j4 * 4 + 2] = h2; qh_l[rr][j4 * 4 + 3] = h3;
        ql_l[rr][j4 * 4 + 0] = f2bf(v.x - bf2f(h0));
        ql_l[rr][j4 * 4 + 1] = f2bf(v.y - bf2f(h1));
        ql_l[rr][j4 * 4 + 2] = f2bf(v.z - bf2f(h2));
        ql_l[rr][j4 * 4 + 3] = f2bf(v.w - bf2f(h3));
    }
    {
        float* prf = &pr_l[0][0];
        for (int i = tid; i < TB * 129; i += 256) prf[i] = 0.f;
    }
    __syncthreads();

    // A fragments (held for whole kernel): A[m=colk][k=quad*8+j], slices 0/1
    short8 ah0 = *(const short8*)&qh_l[colk][quad * 8];
    short8 ah1 = *(const short8*)&qh_l[colk][32 + quad * 8];
    short8 al0 = *(const short8*)&ql_l[colk][quad * 8];
    short8 al1 = *(const short8*)&ql_l[colk][32 + quad * 8];

    // phase 1: qrk[r][c] = q[r] . rpe_k[c], staged 32 rows at a time
    for (int cc = 0; cc < 5; ++cc) {
        const int base = cc * 32;
        for (int i = tid; i < 32 * 16; i += 256) {
            int kr = i >> 4, j4 = i & 15;
            int c = base + kr;
            float4 v = {0.f, 0.f, 0.f, 0.f};
            if (c < 129) v = *(const float4*)(rpe_k + (size_t)c * HDD + j4 * 4);
            *(float4*)&v_l[kr][j4 * 4] = v;
        }
        __syncthreads();
        #pragma unroll
        for (int u = 0; u < 2; ++u) {
            int c = base + g + 16 * u;
            if (c < 129) {
                float a0 = 0.f, a1 = 0.f, a2 = 0.f, a3 = 0.f;
                #pragma unroll
                for (int j4 = 0; j4 < 16; ++j4) {
                    float4 q4 = *(const float4*)&p_ch[r16][j4 * 4];
                    float4 e4 = *(const float4*)&v_l[g + 16 * u][j4 * 4];
                    a0 = fmaf(q4.x, e4.x, a0);
                    a1 = fmaf(q4.y, e4.y, a1);
                    a2 = fmaf(q4.z, e4.z, a2);
                    a3 = fmaf(q4.w, e4.w, a3);
                }
                qrk_l[r16][c] = (a0 + a1) + (a2 + a3);
            }
        }
        __syncthreads();
    }

    // ---------------- pass A: online stats ----------------
    float sm[4], sl[4], sl2[4], sc[4];
    #pragma unroll
    for (int j = 0; j < 4; ++j) { sm[j] = -1e30f; sl[j] = 0.f; sl2[j] = 0.f; sc[j] = 0.f; }

    for (int cc = 0; cc < NCH; ++cc) {
        const int base = cc * CH;
        for (int i = tid; i < CH * 8; i += 256) {
            int kr = i >> 3, j8 = i & 7;
            int key = base + kr;
            float4 hv = {0.f, 0.f, 0.f, 0.f}, lv = {0.f, 0.f, 0.f, 0.f};
            if (key < KLL) {
                size_t o = ((size_t)n * KLL + key) * HDD + j8 * 8;
                hv = *(const float4*)(kh_g + o);
                lv = *(const float4*)(kl_g + o);
            }
            *(float4*)&kh_l[kr][j8 * 8] = hv;
            *(float4*)&kl_l[kr][j8 * 8] = lv;
        }
        __syncthreads();

        const int kk = wv * 16 + colk;
        short8 bh0 = *(const short8*)&kh_l[kk][quad * 8];
        short8 bh1 = *(const short8*)&kh_l[kk][32 + quad * 8];
        short8 bl0 = *(const short8*)&kl_l[kk][quad * 8];
        short8 bl1 = *(const short8*)&kl_l[kk][32 + quad * 8];
        f32x4 c4 = {0.f, 0.f, 0.f, 0.f};
        c4 = __builtin_amdgcn_mfma_f32_16x16x32_bf16(ah0, bh0, c4, 0, 0, 0);
        c4 = __builtin_amdgcn_mfma_f32_16x16x32_bf16(ah1, bh1, c4, 0, 0, 0);
        c4 = __builtin_amdgcn_mfma_f32_16x16x32_bf16(ah0, bl0, c4, 0, 0, 0);
        c4 = __builtin_amdgcn_mfma_f32_16x16x32_bf16(ah1, bl1, c4, 0, 0, 0);
        c4 = __builtin_amdgcn_mfma_f32_16x16x32_bf16(al0, bh0, c4, 0, 0, 0);
        c4 = __builtin_amdgcn_mfma_f32_16x16x32_bf16(al1, bh1, c4, 0, 0, 0);

        const int key = base + wv * 16 + colk;
        if (key < klen) {
            #pragma unroll
            for (int reg = 0; reg < 4; ++reg) {
                const int row = quad * 4 + reg;
                if (row < rows) {
                    const size_t idx = (size_t)(t0 + row) * KLL + key;
                    bool masked;
                    if (mode == 0)      masked = (am_i[idx] != 0);
                    else if (mode == 1) masked = (am_f[idx] != 0.f);
                    else                masked = (am_b[idx] != 0);
                    if (!masked) {
                        float s = c4[reg] + qrk_l[row][rpe[idx]];
                        sc[reg] += 1.f;
                        if (s <= sm[reg]) {
                            float e = expf(s - sm[reg]);
                            sl[reg] += e; sl2[reg] = fmaf(e, e, sl2[reg]);
                        } else {
                            float e = expf(sm[reg] - s);
                            sl[reg] = fmaf(sl[reg], e, 1.f);
                            sl2[reg] = fmaf(sl2[reg], e * e, 1.f);
                            sm[reg] = s;
                        }
                    }
                }
            }
        }
        __syncthreads();
    }

    // merge stats: 16 lanes within quad, then across 4 waves
    #pragma unroll
    for (int reg = 0; reg < 4; ++reg) {
        #pragma unroll
        for (int d = 1; d < 16; d <<= 1) {
            float mo = __shfl_xor(sm[reg], d, 16);
            float lo = __shfl_xor(sl[reg], d, 16);
            float l2o = __shfl_xor(sl2[reg], d, 16);
            float co = __shfl_xor(sc[reg], d, 16);
            float mn = fmaxf(sm[reg], mo);
            float ea = expf(sm[reg] - mn), eb = expf(mo - mn);
            sl[reg] = sl[reg] * ea + lo * eb;
            sl2[reg] = sl2[reg] * ea * ea + l2o * eb * eb;
            sm[reg] = mn; sc[reg] += co;
        }
    }
    if (colk == 0) {
        #pragma unroll
        for (int reg = 0; reg < 4; ++reg)
            stats_l[wv][quad * 4 + reg] = make_float4(sm[reg], sl[reg], sl2[reg], sc[reg]);
    }
    __syncthreads();
    if (tid < TB) {
        float M = -1e30f, L = 0.f, L2 = 0.f, C = 0.f;
        #pragma unroll
        for (int w = 0; w < 4; ++w) {
            float4 s4 = stats_l[w][tid];
            float mn = fmaxf(M, s4.x);
            float ea = expf(M - mn), eb = expf(s4.x - mn);
            L = L * ea + s4.y * eb;
            L2 = L2 * ea * ea + s4.z * eb * eb;
            M = mn; C += s4.w;
        }
        float inv = 1.f / L;
        float mean = 1.f / (C + 1e-8f);     // key_sum == 1
        float sump2 = L2 * inv * inv;
        float var = (sump2 - 2.f * mean + C * mean * mean) / (C - 1.f + 1e-8f);
        var = fmaxf(var, 0.f);
        float thr = mean - 0.5f * sqrtf(var);
        stats_l[0][tid] = make_float4(M, inv, thr, 0.f);
    }
    __syncthreads();

    // ---------------- pass B: recompute + PV ----------------
    float4 acc = {0.f, 0.f, 0.f, 0.f};
    float sig[4] = {0.f, 0.f, 0.f, 0.f};

    for (int cc = 0; cc < NCH; ++cc) {
        const int base = cc * CH;
        // stage K hi/lo
        for (int i = tid; i < CH * 8; i += 256) {
            int kr = i >> 3, j8 = i & 7;
            int key = base + kr;
            float4 hv = {0.f, 0.f, 0.f, 0.f}, lv = {0.f, 0.f, 0.f, 0.f};
            if (key < KLL) {
                size_t o = ((size_t)n * KLL + key) * HDD + j8 * 8;
                hv = *(const float4*)(kh_g + o);
                lv = *(const float4*)(kl_g + o);
            }
            *(float4*)&kh_l[kr][j8 * 8] = hv;
            *(float4*)&kl_l[kr][j8 * 8] = lv;
        }
        // stage V half 0
        for (int i = tid; i < 32 * 16; i += 256) {
            int kr = i >> 4, j4 = i & 15;
            int key = base + kr;
            float4 v = {0.f, 0.f, 0.f, 0.f};
            if (key < KLL) v = *(const float4*)(v_s + ((size_t)n * KLL + key) * HDD + j4 * 4);
            *(float4*)&v_l[kr][j4 * 4] = v;
        }
        __syncthreads();

        const int kk = wv * 16 + colk;
        short8 bh0 = *(const short8*)&kh_l[kk][quad * 8];
        short8 bh1 = *(const short8*)&kh_l[kk][32 + quad * 8];
        short8 bl0 = *(const short8*)&kl_l[kk][quad * 8];
        short8 bl1 = *(const short8*)&kl_l[kk][32 + quad * 8];
        f32x4 c4 = {0.f, 0.f, 0.f, 0.f};
        c4 = __builtin_amdgcn_mfma_f32_16x16x32_bf16(ah0, bh0, c4, 0, 0, 0);
        c4 = __builtin_amdgcn_mfma_f32_16x16x32_bf16(ah1, bh1, c4, 0, 0, 0);
        c4 = __builtin_amdgcn_mfma_f32_16x16x32_bf16(ah0, bl0, c4, 0, 0, 0);
        c4 = __builtin_amdgcn_mfma_f32_16x16x32_bf16(ah1, bl1, c4, 0, 0, 0);
        c4 = __builtin_amdgcn_mfma_f32_16x16x32_bf16(al0, bh0, c4, 0, 0, 0);
        c4 = __builtin_amdgcn_mfma_f32_16x16x32_bf16(al1, bh1, c4, 0, 0, 0);

        const int key = base + wv * 16 + colk;
        #pragma unroll
        for (int reg = 0; reg < 4; ++reg) {
            const int row = quad * 4 + reg;
            float p = 0.f;
            if (row < rows && key < klen) {
                const size_t idx = (size_t)(t0 + row) * KLL + key;
                bool masked;
                if (mode == 0)      masked = (am_i[idx] != 0);
                else if (mode == 1) masked = (am_f[idx] != 0.f);
                else                masked = (am_b[idx] != 0);
                if (!masked) {
                    int rid = rpe[idx];
                    float4 st = stats_l[0][row];        // {m, inv, thr, -}
                    float s = c4[reg] + qrk_l[row][rid];
                    p = expf(s - st.x) * st.y;
                    if (p < st.z) p = 0.f;
                    else { sig[reg] += p; atomicAdd(&pr_l[row][rid], p); }
                }
            }
            p_ch[row][wv * 16 + colk] = p;
        }
        __syncthreads();

        // PV half 0 (keys base..base+31)
        {
            const int kmax = min(32, KLL - base);
            for (int kkv = 0; kkv < kmax; ++kkv) {
                float p = p_ch[r16][kkv];
                if (p != 0.f) {
                    float4 v4 = *(const float4*)&v_l[kkv][g * 4];
                    acc.x = fmaf(p, v4.x, acc.x);
                    acc.y = fmaf(p, v4.y, acc.y);
                    acc.z = fmaf(p, v4.z, acc.z);
                    acc.w = fmaf(p, v4.w, acc.w);
                }
            }
        }
        __syncthreads();
        // stage V half 1
        for (int i = tid; i < 32 * 16; i += 256) {
            int kr = i >> 4, j4 = i & 15;
            int key = base + 32 + kr;
            float4 v = {0.f, 0.f, 0.f, 0.f};
            if (key < KLL) v = *(const float4*)(v_s + ((size_t)n * KLL + key) * HDD + j4 * 4);
            *(float4*)&v_l[kr][j4 * 4] = v;
        }
        __syncthreads();
        // PV half 1 (keys base+32..base+63)
        {
            const int kmax = min(32, KLL - (base + 32));
            for (int kkv = 0; kkv < kmax; ++kkv) {
                float p = p_ch[r16][32 + kkv];
                if (p != 0.f) {
                    float4 v4 = *(const float4*)&v_l[kkv][g * 4];
                    acc.x = fmaf(p, v4.x, acc.x);
                    acc.y = fmaf(p, v4.y, acc.y);
                    acc.z = fmaf(p, v4.z, acc.z);
                    acc.w = fmaf(p, v4.w, acc.w);
                }
            }
        }
        __syncthreads();
    }

    // survivor-sum reduce
    #pragma unroll
    for (int reg = 0; reg < 4; ++reg) {
        #pragma unroll
        for (int d = 1; d < 16; d <<= 1) sig[reg] += __shfl_xor(sig[reg], d, 16);
    }
    if (colk == 0) {
        #pragma unroll
        for (int reg = 0; reg < 4; ++reg)
            stats_l[wv][quad * 4 + reg] = make_float4(sig[reg], 0.f, 0.f, 0.f);
    }
    __syncthreads();
    if (tid < TB) {
        float s = stats_l[0][tid].x + stats_l[1][tid].x + stats_l[2][tid].x + stats_l[3][tid].x;
        stats_l[0][tid].y = 1.f / s;
    }
    __syncthreads();

    if (r16 < rows) {
        float4 ar = {0.f, 0.f, 0.f, 0.f};
        for (int c = 0; c < 129; ++c) {
            float p = pr_l[r16][c];
            if (p != 0.f) {
                float4 v4 = *(const float4*)(rpe_v + (size_t)c * HDD + g * 4);
                ar.x = fmaf(p, v4.x, ar.x);
                ar.y = fmaf(p, v4.y, ar.y);
                ar.z = fmaf(p, v4.z, ar.z);
                ar.w = fmaf(p, v4.w, ar.w);
            }
        }
        const float invS = stats_l[0][r16].y;
        float4 o;
        o.x = (2.f * acc.x + ar.x) * invS;
        o.y = (2.f * acc.y + ar.y) * invS;
        o.z = (2.f * acc.z + ar.z) * invS;
        o.w = (2.f * acc.w + ar.w) * invS;
        *(float4*)(attn_buf + ((size_t)(t0 + r16) * BB + b) * DD + h * HDD + g * 4) = o;
    }
}

__global__ __launch_bounds__(256)
void out_proj_kernel(const float* __restrict__ attn_buf,
                     const float* __restrict__ wo,
                     const float* __restrict__ bo,
                     float* __restrict__ out)
{
    __shared__ float As[16][65];
    __shared__ float Ws[16][65];
    const int tid = threadIdx.x;
    const int m0 = blockIdx.x * 64;
    const int n0 = blockIdx.y * 64;
    const int tx = tid & 15;
    const int ty = tid >> 4;
    float acc[4][4] = {};

    for (int k0 = 0; k0 < DD; k0 += 16) {
        #pragma unroll
        for (int i = 0; i < 4; ++i) {
            int idx = tid + i * 256;
            int kk = idx & 15;
            int mm = idx >> 4;
            int m = m0 + mm;
            As[kk][mm] = (m < NROWS) ? attn_buf[(size_t)m * DD + k0 + kk] : 0.f;
            Ws[kk][mm] = wo[(size_t)(n0 + mm) * DD + k0 + kk];
        }
        __syncthreads();
        #pragma unroll
        for (int kk = 0; kk < 16; ++kk) {
            float a[4], wv[4];
            #pragma unroll
            for (int i = 0; i < 4; ++i) a[i] = As[kk][ty * 4 + i];
            #pragma unroll
            for (int j = 0; j < 4; ++j) wv[j] = Ws[kk][tx * 4 + j];
            #pragma unroll
            for (int i = 0; i < 4; ++i)
                #pragma unroll
                for (int j = 0; j < 4; ++j)
                    acc[i][j] = fmaf(a[i], wv[j], acc[i][j]);
        }
        __syncthreads();
    }

    #pragma unroll
    for (int i = 0; i < 4; ++i) {
        int m = m0 + ty * 4 + i;
        if (m >= NROWS) continue;
        int row = m >> 3;
        #pragma unroll
        for (int j = 0; j < 4; ++j) {
            int n = n0 + tx * 4 + j;
            float v = acc[i][j] + bo[n];
            if (row >= TQ - MMEM) v = tanhf(v);
            out[(size_t)m * DD + n] = v;
        }
    }
}

extern "C" void kernel_launch(void* const* d_in, const int* in_sizes, int n_in,
                              void* d_out, int out_size, void* d_ws, size_t ws_size,
                              hipStream_t stream) {
    const float*          x      = (const float*)d_in[0];
    const int*            lengths= (const int*)d_in[1];
    const float*          mems   = (const float*)d_in[2];
    const void*           amask  = (const void*)d_in[3];
    const int*            rpe    = (const int*)d_in[4];
    const float*          wq     = (const float*)d_in[6];
    const float*          bq     = (const float*)d_in[7];
    const float*          wkv    = (const float*)d_in[8];
    const float*          bkv    = (const float*)d_in[9];
    const float*          wo     = (const float*)d_in[10];
    const float*          bo     = (const float*)d_in[11];
    const float*          rpe_k  = (const float*)d_in[12];
    const float*          rpe_v  = (const float*)d_in[13];

    const size_t NE = (size_t)NHEADS * KLL * HDD;   // 3,268,608 (also = BH*TQ*HDD)
    float* ws       = (float*)d_ws;
    float* q_s      = ws;
    float* v_s      = ws + NE;
    float* attn_buf = ws + 2 * NE;
    unsigned short* k_hi = (unsigned short*)(ws + 3 * NE);
    unsigned short* k_lo = k_hi + NE;
    int*   mmode    = (int*)(k_hi + 2 * NE);

    detect_mask_kernel<<<1, 1024, 0, stream>>>((const unsigned int*)amask, mmode);
    proj_kernel<0><<<dim3(100, 8),  256, 0, stream>>>(x, mems, wq,  bq,  q_s, k_hi, k_lo, v_s);
    proj_kernel<1><<<dim3(100, 16), 256, 0, stream>>>(x, mems, wkv, bkv, q_s, k_hi, k_lo, v_s);
    attn_kernel<<<dim3(50, NHEADS), 256, 0, stream>>>(q_s, k_hi, k_lo, v_s, lengths, amask, mmode,
                                                      rpe, rpe_k, rpe_v, attn_buf);
    out_proj_kernel<<<dim3(100, 8), 256, 0, stream>>>(attn_buf, wo, bo, (float*)d_out);
}